// Round 3
// baseline (397.380 us; speedup 1.0000x reference)
//
#include <hip/hip_runtime.h>
#include <type_traits>
#include <utility>

#define B_ 2
#define S_ 2048
#define D_ 1024
#define H_ 16
#define HD_ 64
#define KDIM 1024

typedef __attribute__((ext_vector_type(8))) short    s16x8;
typedef __attribute__((ext_vector_type(8))) _Float16 h16x8;
typedef __attribute__((ext_vector_type(4))) float    f32x4;
typedef __attribute__((ext_vector_type(4))) int      i32x4;
typedef __attribute__((ext_vector_type(2))) int      i32x2;

// --- MFMA operand-type hedge (fp16) ---
template <typename T, typename = void> struct mfma_takes : std::false_type {};
template <typename T>
struct mfma_takes<T, std::void_t<decltype(__builtin_amdgcn_mfma_f32_16x16x32_f16(
    std::declval<T>(), std::declval<T>(), std::declval<f32x4>(), 0, 0, 0))>>
    : std::true_type {};
using frag8 = std::conditional_t<mfma_takes<h16x8>::value, h16x8, s16x8>;

__device__ __forceinline__ f32x4 mfma_f16(frag8 a, frag8 b, f32x4 c) {
  return __builtin_amdgcn_mfma_f32_16x16x32_f16(a, b, c, 0, 0, 0);
}

__device__ __forceinline__ short f2h(float f) {  // RTNE f32 -> fp16 bits
  _Float16 h = (_Float16)f;
  short s; __builtin_memcpy(&s, &h, 2);
  return s;
}
__device__ __forceinline__ int pk2h(float a, float b) {  // v_cvt_pkrtz 2xfp16
  auto p = __builtin_amdgcn_cvt_pkrtz(a, b);   // __fp16 ext_vector(2)
  int r; __builtin_memcpy(&r, &p, 4); return r;
}
__device__ __forceinline__ frag8 ld_frag(const short* p) {
  return __builtin_bit_cast(frag8, *(const i32x4*)p);
}
__device__ __forceinline__ float fast_exp2(float x) {
  return __builtin_amdgcn_exp2f(x);
}

typedef __attribute__((address_space(1))) const void gvoid;
typedef __attribute__((address_space(3))) void lvoid;
__device__ __forceinline__ void async_copy16(const void* g, void* l) {
  __builtin_amdgcn_global_load_lds((gvoid*)g, (lvoid*)l, 16, 0, 0);
}

#define RAW_BARRIER() asm volatile("s_barrier" ::: "memory")
#define WAITCNT_VM(n) asm volatile("s_waitcnt vmcnt(" #n ")" ::: "memory")

// ---------------------------------------------------------------------------
// Fused fp32 -> fp16 converts: q,k,v (2048 blocks each) + 4 weights (512 each)
// ---------------------------------------------------------------------------
__global__ __launch_bounds__(256)
void conv_all(const float* __restrict__ q, const float* __restrict__ k,
              const float* __restrict__ v, const float* __restrict__ Wq,
              const float* __restrict__ Wk, const float* __restrict__ Wv,
              const float* __restrict__ Wo,
              short* __restrict__ qh, short* __restrict__ kh,
              short* __restrict__ vh, short* __restrict__ wq,
              short* __restrict__ wk, short* __restrict__ wv,
              short* __restrict__ wo) {
  const int blk = blockIdx.x;
  const float* src; short* dst; int base;
  if (blk < 2048)      { src = q;  dst = qh; base = blk; }
  else if (blk < 4096) { src = k;  dst = kh; base = blk - 2048; }
  else if (blk < 6144) { src = v;  dst = vh; base = blk - 4096; }
  else if (blk < 6656) { src = Wq; dst = wq; base = blk - 6144; }
  else if (blk < 7168) { src = Wk; dst = wk; base = blk - 6656; }
  else if (blk < 7680) { src = Wv; dst = wv; base = blk - 7168; }
  else                 { src = Wo; dst = wo; base = blk - 7680; }
  const int i = base * 2048 + threadIdx.x * 8;
  float4 a0 = *(const float4*)(src + i);
  float4 a1 = *(const float4*)(src + i + 4);
  short h[8] = { f2h(a0.x), f2h(a0.y), f2h(a0.z), f2h(a0.w),
                 f2h(a1.x), f2h(a1.y), f2h(a1.z), f2h(a1.w) };
  i32x4 ph; __builtin_memcpy(&ph, h, 16);
  *(i32x4*)(dst + i) = ph;
}

// ---------------------------------------------------------------------------
// QKV projection GEMM, fp16 A & W, tile 128x128, BK=32, triple-buffered
// global_load_lds (prefetch distance 2). A-GROUPED XCD DECODE: all 8 bn
// blocks sharing one A-tile (z,bm) land on the same XCD (xcd = p&7 via
// p=(i>>3)*8+xcd), so each A tile is L2-filled once.
// ---------------------------------------------------------------------------
__global__ __launch_bounds__(256, 3)
void gemm_qkv(const short* __restrict__ qh, const short* __restrict__ kh,
              const short* __restrict__ vh, const short* __restrict__ wq,
              const short* __restrict__ wk, const short* __restrict__ wv,
              const float* __restrict__ bq, const float* __restrict__ bk,
              const float* __restrict__ bv, short* __restrict__ Qf,
              short* __restrict__ Kf, short* __restrict__ Vt, float QS) {
  __shared__ short As[3 * 4096];
  __shared__ short Bs[3 * 4096];

  const int blk = blockIdx.x;
  const int xcd = blk & 7, i = blk >> 3;      // i in [0,96)
  const int p = (i >> 3) * 8 + xcd;           // A-tile id, p ≡ xcd (mod 8)
  const int bn = i & 7;
  const int z = p >> 5, bm = p & 31;
  const short* Ap = z == 0 ? qh : z == 1 ? kh : vh;
  const short* Wp = z == 0 ? wq : z == 1 ? wk : wv;
  const float* bias = z == 0 ? bq : z == 1 ? bk : bv;
  short* Out = z == 0 ? Qf : z == 1 ? Kf : Vt;
  const float scale = z == 0 ? QS : 1.0f;
  const int omode = z == 2 ? 2 : 1;

  const int t = threadIdx.x, wave = t >> 6, lane = t & 63;
  const int laneN = lane & 15, quad = lane >> 4;
  const int wm = wave & 1, wn = wave >> 1;

  f32x4 acc[4][4];
#pragma unroll
  for (int i2 = 0; i2 < 4; ++i2)
#pragma unroll
    for (int j = 0; j < 4; ++j)
#pragma unroll
      for (int r = 0; r < 4; ++r) acc[i2][j][r] = 0.f;

  auto stage = [&](int buf, int kk) {   // 4 asyncs/thread per call
#pragma unroll
    for (int j = 0; j < 2; ++j) {
      const int chunk = j * 256 + t;
      const int row = chunk >> 2;
      const int gg = (chunk & 3) ^ ((row >> 1) & 3);
      async_copy16(Ap + (size_t)(bm * 128 + row) * KDIM + kk + gg * 8,
                   As + buf * 4096 + chunk * 8);
      async_copy16(Wp + (size_t)(bn * 128 + row) * KDIM + kk + gg * 8,
                   Bs + buf * 4096 + chunk * 8);
    }
  };

  stage(0, 0);
  stage(1, 32);
  int buf = 0;
  for (int kk = 0; kk < KDIM; kk += 32) {
    if (kk + 64 < KDIM) {
      int nb = buf + 2; if (nb >= 3) nb -= 3;
      stage(nb, kk + 64);
      WAITCNT_VM(8);        // drain current tile (oldest 4 of 12)
    } else if (kk + 32 < KDIM) {
      WAITCNT_VM(4);
    } else {
      WAITCNT_VM(0);
    }
    RAW_BARRIER();

    frag8 aF[4], bF[4];
#pragma unroll
    for (int mi = 0; mi < 4; ++mi) {
      const int row = wm * 64 + mi * 16 + laneN;
      aF[mi] = ld_frag(As + buf * 4096 + row * 32 +
                       ((quad ^ ((row >> 1) & 3)) * 8));
    }
#pragma unroll
    for (int ni = 0; ni < 4; ++ni) {
      const int row = wn * 64 + ni * 16 + laneN;
      bF[ni] = ld_frag(Bs + buf * 4096 + row * 32 +
                       ((quad ^ ((row >> 1) & 3)) * 8));
    }
#pragma unroll
    for (int mi = 0; mi < 4; ++mi)
#pragma unroll
      for (int ni = 0; ni < 4; ++ni)
        acc[mi][ni] = mfma_f16(aF[mi], bF[ni], acc[mi][ni]);
    RAW_BARRIER();
    buf = buf + 1 == 3 ? 0 : buf + 1;
  }

  // Epilogue. C/D: col = lane&15, row = quad*4 + reg.
#pragma unroll
  for (int mi = 0; mi < 4; ++mi)
#pragma unroll
    for (int ni = 0; ni < 4; ++ni) {
      const int colg = bn * 128 + wn * 64 + ni * 16 + laneN;
      const float bb = bias[colg];
      if (omode == 2) {
        // Vt [B,H,Hd,S]: r -> 4 consecutive s, same hd -> one b64 store
        const int rowg0 = bm * 128 + wm * 64 + mi * 16 + quad * 4;
        const int b = rowg0 >> 11, s0 = rowg0 & 2047;
        const int h = colg >> 6, hd = colg & 63;
        short pk[4];
#pragma unroll
        for (int r = 0; r < 4; ++r) pk[r] = f2h(acc[mi][ni][r] + bb);
        i32x2 w; __builtin_memcpy(&w, pk, 8);
        *(i32x2*)(Vt + (((size_t)(b * H_ + h)) * HD_ + hd) * S_ + s0) = w;
      } else {
#pragma unroll
        for (int r = 0; r < 4; ++r) {
          const int rowg = bm * 128 + wm * 64 + mi * 16 + quad * 4 + r;
          const int b = rowg >> 11, s = rowg & 2047;
          const int h = colg >> 6, hd = colg & 63;
          Out[(((size_t)(b * H_ + h)) * S_ + s) * HD_ + hd] =
              f2h((acc[mi][ni][r] + bb) * scale);
        }
      }
    }
}

// ---------------------------------------------------------------------------
// O projection: fp16 A x fp16 Wo -> fp32. Tile 128(M)x64(N), triple-buffered
// prefetch distance 2. A-GROUPED XCD DECODE: all 16 bn blocks sharing one
// A-tile (bm) on the same XCD (bm ≡ xcd mod 8); Wo (2 MB) fits per-XCD L2.
// ---------------------------------------------------------------------------
__global__ __launch_bounds__(256, 3)
void gemm_out(const short* __restrict__ Ap, const short* __restrict__ Wp,
              const float* __restrict__ bias, float* __restrict__ Out) {
  __shared__ short As[3 * 4096];   // 128x32
  __shared__ short Bs[3 * 2048];   // 64x32
  const int blk = blockIdx.x;
  const int xcd = blk & 7, i = blk >> 3;      // i in [0,64)
  const int bm = (i >> 4) * 8 + xcd;          // bm ≡ xcd (mod 8)
  const int bn = i & 15;

  const int t = threadIdx.x, wave = t >> 6, lane = t & 63;
  const int laneN = lane & 15, quad = lane >> 4;
  const int wm = wave & 1, wn = wave >> 1;

  f32x4 acc[4][2];
#pragma unroll
  for (int i2 = 0; i2 < 4; ++i2)
#pragma unroll
    for (int j = 0; j < 2; ++j)
#pragma unroll
      for (int r = 0; r < 4; ++r) acc[i2][j][r] = 0.f;

  auto stage = [&](int buf, int kk) {   // 3 asyncs/thread per call
#pragma unroll
    for (int j = 0; j < 2; ++j) {
      const int chunk = j * 256 + t;
      const int row = chunk >> 2;
      const int gg = (chunk & 3) ^ ((row >> 1) & 3);
      async_copy16(Ap + (size_t)(bm * 128 + row) * KDIM + kk + gg * 8,
                   As + buf * 4096 + chunk * 8);
    }
    {
      const int chunk = t;
      const int row = chunk >> 2;
      const int gg = (chunk & 3) ^ ((row >> 1) & 3);
      async_copy16(Wp + (size_t)(bn * 64 + row) * KDIM + kk + gg * 8,
                   Bs + buf * 2048 + chunk * 8);
    }
  };

  stage(0, 0);
  stage(1, 32);
  int buf = 0;
  for (int kk = 0; kk < KDIM; kk += 32) {
    if (kk + 64 < KDIM) {
      int nb = buf + 2; if (nb >= 3) nb -= 3;
      stage(nb, kk + 64);
      WAITCNT_VM(6);
    } else if (kk + 32 < KDIM) {
      WAITCNT_VM(3);
    } else {
      WAITCNT_VM(0);
    }
    RAW_BARRIER();

    frag8 aF[4], bF[2];
#pragma unroll
    for (int mi = 0; mi < 4; ++mi) {
      const int row = wm * 64 + mi * 16 + laneN;
      aF[mi] = ld_frag(As + buf * 4096 + row * 32 +
                       ((quad ^ ((row >> 1) & 3)) * 8));
    }
#pragma unroll
    for (int ni = 0; ni < 2; ++ni) {
      const int row = wn * 32 + ni * 16 + laneN;
      bF[ni] = ld_frag(Bs + buf * 2048 + row * 32 +
                       ((quad ^ ((row >> 1) & 3)) * 8));
    }
#pragma unroll
    for (int mi = 0; mi < 4; ++mi)
#pragma unroll
      for (int ni = 0; ni < 2; ++ni)
        acc[mi][ni] = mfma_f16(aF[mi], bF[ni], acc[mi][ni]);
    RAW_BARRIER();
    buf = buf + 1 == 3 ? 0 : buf + 1;
  }

#pragma unroll
  for (int mi = 0; mi < 4; ++mi)
#pragma unroll
    for (int ni = 0; ni < 2; ++ni) {
      const int colg = bn * 64 + wn * 32 + ni * 16 + laneN;
      const float bb = bias[colg];
#pragma unroll
      for (int r = 0; r < 4; ++r) {
        const int rowg = bm * 128 + wm * 64 + mi * 16 + quad * 4 + r;
        Out[(size_t)rowg * 1024 + colg] = acc[mi][ni][r] + bb;
      }
    }
}

// ---------------------------------------------------------------------------
// Flash attention, fp16. R11: R0's proven shape (512 blocks x 512 threads,
// 8 waves x 16 q, 16 waves/CU) but K/V LDS STAGING REMOVED — fragments are
// loaded straight from global. Rationale (R1/R2 post-mortems): both
// restructures cut waves/CU and regressed; R0's limiter is the serial
// per-wave chain + barrier lockstep (2 barriers + vmcnt drain per kt), not
// LDS bandwidth. Per-XCD working set = 4 pairs x 512KB = 2MB < 4MB L2
// (guide m169: drop LDS staging when data cache-fits); the 16KB/kt tile is
// L1-multicast across the block's 16 waves. NO barriers remain — waves
// free-run. LDS holds only the per-wave P strip (16KB). Per-kt addressing
// is one uniform pointer bump (SGPR) + invariant per-lane offsets, halves
// folded into the load offset immediate. Defer-max (THR=8), tree
// reductions, rotated stride-64 P strip kept (verified R1/R2).
// K frag (nt,half): row k=nt*16+laneN (stride 128B), bytes half*64+quad*16
// -> 16x64B segments/load, half pairs complete 128B lines. V same on
// [B,H,Hd,S] (row stride 4KB).
// ---------------------------------------------------------------------------
__global__ __launch_bounds__(512, 4)
void attn(const short* __restrict__ Qf, const short* __restrict__ Kf,
          const short* __restrict__ Vt_, short* __restrict__ Ow) {
  __shared__ short Ps[8][16 * 64];   // per-wave P strip [q][k], stride 64

  // XCD-locality: 512 blocks = 8 XCDs x 4 (h,b) pairs x 16 q-tiles of 128
  const int blk = blockIdx.x;
  const int xcd = blk & 7, local = blk >> 3;     // local 0..63
  const int pair = xcd * 4 + (local >> 4);       // 0..31
  const int h = pair & 15, b = pair >> 4, qt = local & 15;
  const size_t head = ((size_t)b * H_ + h) * (size_t)S_ * HD_;

  const int t = threadIdx.x;
  const int wave = t >> 6, lane = t & 63;
  const int laneN = lane & 15, quad = lane >> 4;

  // Q frags (B-operand); wave owns 16 q rows
  frag8 qf[2];
  {
    const size_t row = (size_t)qt * 128 + wave * 16 + laneN;
#pragma unroll
    for (int half = 0; half < 2; ++half)
      qf[half] = ld_frag(Qf + head + row * HD_ + half * 32 + quad * 8);
  }

  f32x4 o[4];          // O^T: row d = dt*16+quad*4+r, col q = laneN
  float m_r = -1e30f, l_r = 0.f;
#pragma unroll
  for (int i = 0; i < 4; ++i)
#pragma unroll
    for (int j = 0; j < 4; ++j) o[i][j] = 0.f;

  // invariant per-lane offsets (shorts) within a kt tile; halves via +32
  int koff[4], voff[4];
#pragma unroll
  for (int nt = 0; nt < 4; ++nt) {
    koff[nt] = (nt * 16 + laneN) * HD_ + quad * 8;
    voff[nt] = (nt * 16 + laneN) * S_ + quad * 8;
  }

  // per-lane invariant P-strip addresses (rotated slot = (g + q) & 7)
  short* const pwr = &Ps[wave][0] + laneN * 64;
  const int rd0 = ((quad + laneN) & 7) * 8;        // k 0..31
  const int rd1 = (((quad + 4) + laneN) & 7) * 8;  // k 32..63

  const short* Kt = Kf + head;    // += 64*HD_ shorts per kt (uniform)
  const short* Vp = Vt_ + head;   // += 64 shorts per kt (uniform)

  for (int kt = 0; kt < 32; ++kt, Kt += 64 * HD_, Vp += 64) {
    // K fragments: issue all 8 loads, consume in MFMA (ILP)
    frag8 kf[4][2];
#pragma unroll
    for (int nt = 0; nt < 4; ++nt) {
      kf[nt][0] = ld_frag(Kt + koff[nt]);
      kf[nt][1] = ld_frag(Kt + koff[nt] + 32);
    }

    // S^T = K.Q^T: per lane 16 logits for q=laneN, k = nt*16+quad*4+r
    f32x4 s[4];
#pragma unroll
    for (int nt = 0; nt < 4; ++nt) {
      f32x4 acc;
#pragma unroll
      for (int j = 0; j < 4; ++j) acc[j] = 0.f;
      acc = mfma_f16(kf[nt][0], qf[0], acc);
      acc = mfma_f16(kf[nt][1], qf[1], acc);
      s[nt] = acc;
    }

    // V fragments: issue now, latency hidden under softmax
    frag8 vf[4][2];
#pragma unroll
    for (int dt = 0; dt < 4; ++dt) {
      vf[dt][0] = ld_frag(Vp + voff[dt]);
      vf[dt][1] = ld_frag(Vp + voff[dt] + 32);
    }

    // online softmax (exp2 domain), tree reduce + defer-max (THR=8)
    {
      float mt[4];
#pragma unroll
      for (int nt = 0; nt < 4; ++nt)
        mt[nt] = fmaxf(fmaxf(s[nt][0], s[nt][1]), fmaxf(s[nt][2], s[nt][3]));
      float mx = fmaxf(fmaxf(mt[0], mt[1]), fmaxf(mt[2], mt[3]));
      mx = fmaxf(mx, __shfl_xor(mx, 16));
      mx = fmaxf(mx, __shfl_xor(mx, 32));
      if (__any(mx > m_r + 8.f)) {     // wave-uniform: rescale rarely
        const float mn = fmaxf(m_r, mx);
        const float al = fast_exp2(m_r - mn);
        m_r = mn;
        l_r *= al;
#pragma unroll
        for (int dt = 0; dt < 4; ++dt)
#pragma unroll
          for (int r = 0; r < 4; ++r) o[dt][r] *= al;
      }
      float rt[4];
#pragma unroll
      for (int nt = 0; nt < 4; ++nt) {
        const float p0 = fast_exp2(s[nt][0] - m_r);
        const float p1 = fast_exp2(s[nt][1] - m_r);
        const float p2 = fast_exp2(s[nt][2] - m_r);
        const float p3 = fast_exp2(s[nt][3] - m_r);
        s[nt][0] = p0; s[nt][1] = p1; s[nt][2] = p2; s[nt][3] = p3;
        rt[nt] = (p0 + p1) + (p2 + p3);
      }
      float rs = (rt[0] + rt[1]) + (rt[2] + rt[3]);
      rs += __shfl_xor(rs, 16);
      rs += __shfl_xor(rs, 32);
      l_r += rs;
    }

    // P pack: 4 consecutive k per nt -> one b64 write at rotated slot
#pragma unroll
    for (int nt = 0; nt < 4; ++nt) {
      i32x2 w;
      w[0] = pk2h(s[nt][0], s[nt][1]);
      w[1] = pk2h(s[nt][2], s[nt][3]);
      const int g = nt * 2 + (quad >> 1);          // k-block index
      const int slot = (g + laneN) & 7;            // rotated placement
      *(i32x2*)(pwr + slot * 8 + (quad & 1) * 4) = w;
    }
    // B-operand P frags (per-wave strip; in-order DS within a wave)
    const frag8 p0 = ld_frag(pwr + rd0);
    const frag8 p1 = ld_frag(pwr + rd1);
#pragma unroll
    for (int dt = 0; dt < 4; ++dt) {
      o[dt] = mfma_f16(vf[dt][0], p0, o[dt]);
      o[dt] = mfma_f16(vf[dt][1], p1, o[dt]);
    }
  }

  // epilogue: O^T -> Ow[B,S,D] fp16; lane owns q, 4 consecutive d per dt
  {
    const float inv = 1.0f / l_r;
    const int sg = qt * 128 + wave * 16 + laneN;
    short* dst = Ow + ((size_t)b * S_ + sg) * D_ + h * HD_;
#pragma unroll
    for (int dt = 0; dt < 4; ++dt) {
      short pk[4] = { f2h(o[dt][0] * inv), f2h(o[dt][1] * inv),
                      f2h(o[dt][2] * inv), f2h(o[dt][3] * inv) };
      i32x2 w; __builtin_memcpy(&w, pk, 8);
      *(i32x2*)(dst + dt * 16 + quad * 4) = w;
    }
  }
}

// ---------------------------------------------------------------------------
extern "C" void kernel_launch(void* const* d_in, const int* in_sizes, int n_in,
                              void* d_out, int out_size, void* d_ws, size_t ws_size,
                              hipStream_t stream) {
  const float* q  = (const float*)d_in[0];
  const float* k  = (const float*)d_in[1];
  const float* v  = (const float*)d_in[2];
  const float* Wq = (const float*)d_in[3];
  const float* bq = (const float*)d_in[4];
  const float* Wk = (const float*)d_in[5];
  const float* bk = (const float*)d_in[6];
  const float* Wv = (const float*)d_in[7];
  const float* bv = (const float*)d_in[8];
  const float* Wo = (const float*)d_in[9];
  const float* bo = (const float*)d_in[10];

  const size_t NTOK = (size_t)B_ * S_ * D_;   // 4,194,304
  const size_t NW   = (size_t)D_ * D_;        // 1,048,576
  short* p = (short*)d_ws;
  short* qh = p; p += NTOK;  short* kh = p; p += NTOK;  short* vh = p; p += NTOK;
  short* wq = p; p += NW;    short* wk = p; p += NW;
  short* wv = p; p += NW;    short* wo = p; p += NW;
  short* Qf = p; p += NTOK;  short* Kf = p; p += NTOK;
  short* Vt = p; p += NTOK;  short* Ow = p; p += NTOK;

  dim3 blk(256);

  conv_all<<<8192, blk, 0, stream>>>(q, k, v, Wq, Wk, Wv, Wo,
                                     qh, kh, vh, wq, wk, wv, wo);

  const float QS = 11.541560327111707f;  // 8 * log2(e): exp2-domain softmax
  gemm_qkv<<<768, blk, 0, stream>>>(qh, kh, vh, wq, wk, wv, bq, bk, bv,
                                    Qf, Kf, Vt, QS);

  attn<<<512, dim3(512), 0, stream>>>(Qf, Kf, Vt, Ow);

  gemm_out<<<512, blk, 0, stream>>>(Ow, wo, bo, (float*)d_out);
}

// Round 4
// 225.387 us; speedup vs baseline: 1.7631x; 1.7631x over previous
//
#include <hip/hip_runtime.h>
#include <type_traits>
#include <utility>

#define B_ 2
#define S_ 2048
#define D_ 1024
#define H_ 16
#define HD_ 64
#define KDIM 1024

typedef __attribute__((ext_vector_type(8))) short    s16x8;
typedef __attribute__((ext_vector_type(8))) _Float16 h16x8;
typedef __attribute__((ext_vector_type(4))) float    f32x4;
typedef __attribute__((ext_vector_type(4))) int      i32x4;
typedef __attribute__((ext_vector_type(2))) int      i32x2;

// --- MFMA operand-type hedge (fp16) ---
template <typename T, typename = void> struct mfma_takes : std::false_type {};
template <typename T>
struct mfma_takes<T, std::void_t<decltype(__builtin_amdgcn_mfma_f32_16x16x32_f16(
    std::declval<T>(), std::declval<T>(), std::declval<f32x4>(), 0, 0, 0))>>
    : std::true_type {};
using frag8 = std::conditional_t<mfma_takes<h16x8>::value, h16x8, s16x8>;

__device__ __forceinline__ f32x4 mfma_f16(frag8 a, frag8 b, f32x4 c) {
  return __builtin_amdgcn_mfma_f32_16x16x32_f16(a, b, c, 0, 0, 0);
}

__device__ __forceinline__ short f2h(float f) {  // RTNE f32 -> fp16 bits
  _Float16 h = (_Float16)f;
  short s; __builtin_memcpy(&s, &h, 2);
  return s;
}
__device__ __forceinline__ int pk2h(float a, float b) {  // v_cvt_pkrtz 2xfp16
  auto p = __builtin_amdgcn_cvt_pkrtz(a, b);   // __fp16 ext_vector(2)
  int r; __builtin_memcpy(&r, &p, 4); return r;
}
__device__ __forceinline__ frag8 ld_frag(const short* p) {
  return __builtin_bit_cast(frag8, *(const i32x4*)p);
}
__device__ __forceinline__ float fast_exp2(float x) {
  return __builtin_amdgcn_exp2f(x);
}

typedef __attribute__((address_space(1))) const void gvoid;
typedef __attribute__((address_space(3))) void lvoid;
__device__ __forceinline__ void async_copy16(const void* g, void* l) {
  __builtin_amdgcn_global_load_lds((gvoid*)g, (lvoid*)l, 16, 0, 0);
}

#define RAW_BARRIER() asm volatile("s_barrier" ::: "memory")
#define WAITCNT_VM(n) asm volatile("s_waitcnt vmcnt(" #n ")" ::: "memory")

// ---------------------------------------------------------------------------
// Fused fp32 -> fp16 converts: q,k,v (2048 blocks each) + 4 weights (512 each)
// ---------------------------------------------------------------------------
__global__ __launch_bounds__(256)
void conv_all(const float* __restrict__ q, const float* __restrict__ k,
              const float* __restrict__ v, const float* __restrict__ Wq,
              const float* __restrict__ Wk, const float* __restrict__ Wv,
              const float* __restrict__ Wo,
              short* __restrict__ qh, short* __restrict__ kh,
              short* __restrict__ vh, short* __restrict__ wq,
              short* __restrict__ wk, short* __restrict__ wv,
              short* __restrict__ wo) {
  const int blk = blockIdx.x;
  const float* src; short* dst; int base;
  if (blk < 2048)      { src = q;  dst = qh; base = blk; }
  else if (blk < 4096) { src = k;  dst = kh; base = blk - 2048; }
  else if (blk < 6144) { src = v;  dst = vh; base = blk - 4096; }
  else if (blk < 6656) { src = Wq; dst = wq; base = blk - 6144; }
  else if (blk < 7168) { src = Wk; dst = wk; base = blk - 6656; }
  else if (blk < 7680) { src = Wv; dst = wv; base = blk - 7168; }
  else                 { src = Wo; dst = wo; base = blk - 7680; }
  const int i = base * 2048 + threadIdx.x * 8;
  float4 a0 = *(const float4*)(src + i);
  float4 a1 = *(const float4*)(src + i + 4);
  short h[8] = { f2h(a0.x), f2h(a0.y), f2h(a0.z), f2h(a0.w),
                 f2h(a1.x), f2h(a1.y), f2h(a1.z), f2h(a1.w) };
  i32x4 ph; __builtin_memcpy(&ph, h, 16);
  *(i32x4*)(dst + i) = ph;
}

// ---------------------------------------------------------------------------
// QKV projection GEMM, fp16 A & W, tile 128x128, BK=32, triple-buffered
// global_load_lds (prefetch distance 2). A-GROUPED XCD DECODE: all 8 bn
// blocks sharing one A-tile (z,bm) land on the same XCD (xcd = p&7 via
// p=(i>>3)*8+xcd), so each A tile is L2-filled once.
// ---------------------------------------------------------------------------
__global__ __launch_bounds__(256, 3)
void gemm_qkv(const short* __restrict__ qh, const short* __restrict__ kh,
              const short* __restrict__ vh, const short* __restrict__ wq,
              const short* __restrict__ wk, const short* __restrict__ wv,
              const float* __restrict__ bq, const float* __restrict__ bk,
              const float* __restrict__ bv, short* __restrict__ Qf,
              short* __restrict__ Kf, short* __restrict__ Vt, float QS) {
  __shared__ short As[3 * 4096];
  __shared__ short Bs[3 * 4096];

  const int blk = blockIdx.x;
  const int xcd = blk & 7, i = blk >> 3;      // i in [0,96)
  const int p = (i >> 3) * 8 + xcd;           // A-tile id, p ≡ xcd (mod 8)
  const int bn = i & 7;
  const int z = p >> 5, bm = p & 31;
  const short* Ap = z == 0 ? qh : z == 1 ? kh : vh;
  const short* Wp = z == 0 ? wq : z == 1 ? wk : wv;
  const float* bias = z == 0 ? bq : z == 1 ? bk : bv;
  short* Out = z == 0 ? Qf : z == 1 ? Kf : Vt;
  const float scale = z == 0 ? QS : 1.0f;
  const int omode = z == 2 ? 2 : 1;

  const int t = threadIdx.x, wave = t >> 6, lane = t & 63;
  const int laneN = lane & 15, quad = lane >> 4;
  const int wm = wave & 1, wn = wave >> 1;

  f32x4 acc[4][4];
#pragma unroll
  for (int i2 = 0; i2 < 4; ++i2)
#pragma unroll
    for (int j = 0; j < 4; ++j)
#pragma unroll
      for (int r = 0; r < 4; ++r) acc[i2][j][r] = 0.f;

  auto stage = [&](int buf, int kk) {   // 4 asyncs/thread per call
#pragma unroll
    for (int j = 0; j < 2; ++j) {
      const int chunk = j * 256 + t;
      const int row = chunk >> 2;
      const int gg = (chunk & 3) ^ ((row >> 1) & 3);
      async_copy16(Ap + (size_t)(bm * 128 + row) * KDIM + kk + gg * 8,
                   As + buf * 4096 + chunk * 8);
      async_copy16(Wp + (size_t)(bn * 128 + row) * KDIM + kk + gg * 8,
                   Bs + buf * 4096 + chunk * 8);
    }
  };

  stage(0, 0);
  stage(1, 32);
  int buf = 0;
  for (int kk = 0; kk < KDIM; kk += 32) {
    if (kk + 64 < KDIM) {
      int nb = buf + 2; if (nb >= 3) nb -= 3;
      stage(nb, kk + 64);
      WAITCNT_VM(8);        // drain current tile (oldest 4 of 12)
    } else if (kk + 32 < KDIM) {
      WAITCNT_VM(4);
    } else {
      WAITCNT_VM(0);
    }
    RAW_BARRIER();

    frag8 aF[4], bF[4];
#pragma unroll
    for (int mi = 0; mi < 4; ++mi) {
      const int row = wm * 64 + mi * 16 + laneN;
      aF[mi] = ld_frag(As + buf * 4096 + row * 32 +
                       ((quad ^ ((row >> 1) & 3)) * 8));
    }
#pragma unroll
    for (int ni = 0; ni < 4; ++ni) {
      const int row = wn * 64 + ni * 16 + laneN;
      bF[ni] = ld_frag(Bs + buf * 4096 + row * 32 +
                       ((quad ^ ((row >> 1) & 3)) * 8));
    }
#pragma unroll
    for (int mi = 0; mi < 4; ++mi)
#pragma unroll
      for (int ni = 0; ni < 4; ++ni)
        acc[mi][ni] = mfma_f16(aF[mi], bF[ni], acc[mi][ni]);
    RAW_BARRIER();
    buf = buf + 1 == 3 ? 0 : buf + 1;
  }

  // Epilogue. C/D: col = lane&15, row = quad*4 + reg.
#pragma unroll
  for (int mi = 0; mi < 4; ++mi)
#pragma unroll
    for (int ni = 0; ni < 4; ++ni) {
      const int colg = bn * 128 + wn * 64 + ni * 16 + laneN;
      const float bb = bias[colg];
      if (omode == 2) {
        // Vt [B,H,Hd,S]: r -> 4 consecutive s, same hd -> one b64 store
        const int rowg0 = bm * 128 + wm * 64 + mi * 16 + quad * 4;
        const int b = rowg0 >> 11, s0 = rowg0 & 2047;
        const int h = colg >> 6, hd = colg & 63;
        short pk[4];
#pragma unroll
        for (int r = 0; r < 4; ++r) pk[r] = f2h(acc[mi][ni][r] + bb);
        i32x2 w; __builtin_memcpy(&w, pk, 8);
        *(i32x2*)(Vt + (((size_t)(b * H_ + h)) * HD_ + hd) * S_ + s0) = w;
      } else {
#pragma unroll
        for (int r = 0; r < 4; ++r) {
          const int rowg = bm * 128 + wm * 64 + mi * 16 + quad * 4 + r;
          const int b = rowg >> 11, s = rowg & 2047;
          const int h = colg >> 6, hd = colg & 63;
          Out[(((size_t)(b * H_ + h)) * S_ + s) * HD_ + hd] =
              f2h((acc[mi][ni][r] + bb) * scale);
        }
      }
    }
}

// ---------------------------------------------------------------------------
// O projection: fp16 A x fp16 Wo -> fp32. Tile 128(M)x64(N), triple-buffered
// prefetch distance 2. A-GROUPED XCD DECODE: all 16 bn blocks sharing one
// A-tile (bm) on the same XCD (bm ≡ xcd mod 8); Wo (2 MB) fits per-XCD L2.
// ---------------------------------------------------------------------------
__global__ __launch_bounds__(256, 3)
void gemm_out(const short* __restrict__ Ap, const short* __restrict__ Wp,
              const float* __restrict__ bias, float* __restrict__ Out) {
  __shared__ short As[3 * 4096];   // 128x32
  __shared__ short Bs[3 * 2048];   // 64x32
  const int blk = blockIdx.x;
  const int xcd = blk & 7, i = blk >> 3;      // i in [0,64)
  const int bm = (i >> 4) * 8 + xcd;          // bm ≡ xcd (mod 8)
  const int bn = i & 15;

  const int t = threadIdx.x, wave = t >> 6, lane = t & 63;
  const int laneN = lane & 15, quad = lane >> 4;
  const int wm = wave & 1, wn = wave >> 1;

  f32x4 acc[4][2];
#pragma unroll
  for (int i2 = 0; i2 < 4; ++i2)
#pragma unroll
    for (int j = 0; j < 2; ++j)
#pragma unroll
      for (int r = 0; r < 4; ++r) acc[i2][j][r] = 0.f;

  auto stage = [&](int buf, int kk) {   // 3 asyncs/thread per call
#pragma unroll
    for (int j = 0; j < 2; ++j) {
      const int chunk = j * 256 + t;
      const int row = chunk >> 2;
      const int gg = (chunk & 3) ^ ((row >> 1) & 3);
      async_copy16(Ap + (size_t)(bm * 128 + row) * KDIM + kk + gg * 8,
                   As + buf * 4096 + chunk * 8);
    }
    {
      const int chunk = t;
      const int row = chunk >> 2;
      const int gg = (chunk & 3) ^ ((row >> 1) & 3);
      async_copy16(Wp + (size_t)(bn * 64 + row) * KDIM + kk + gg * 8,
                   Bs + buf * 2048 + chunk * 8);
    }
  };

  stage(0, 0);
  stage(1, 32);
  int buf = 0;
  for (int kk = 0; kk < KDIM; kk += 32) {
    if (kk + 64 < KDIM) {
      int nb = buf + 2; if (nb >= 3) nb -= 3;
      stage(nb, kk + 64);
      WAITCNT_VM(6);
    } else if (kk + 32 < KDIM) {
      WAITCNT_VM(3);
    } else {
      WAITCNT_VM(0);
    }
    RAW_BARRIER();

    frag8 aF[4], bF[2];
#pragma unroll
    for (int mi = 0; mi < 4; ++mi) {
      const int row = wm * 64 + mi * 16 + laneN;
      aF[mi] = ld_frag(As + buf * 4096 + row * 32 +
                       ((quad ^ ((row >> 1) & 3)) * 8));
    }
#pragma unroll
    for (int ni = 0; ni < 2; ++ni) {
      const int row = wn * 32 + ni * 16 + laneN;
      bF[ni] = ld_frag(Bs + buf * 2048 + row * 32 +
                       ((quad ^ ((row >> 1) & 3)) * 8));
    }
#pragma unroll
    for (int mi = 0; mi < 4; ++mi)
#pragma unroll
      for (int ni = 0; ni < 2; ++ni)
        acc[mi][ni] = mfma_f16(aF[mi], bF[ni], acc[mi][ni]);
    RAW_BARRIER();
    buf = buf + 1 == 3 ? 0 : buf + 1;
  }

#pragma unroll
  for (int mi = 0; mi < 4; ++mi)
#pragma unroll
    for (int ni = 0; ni < 2; ++ni) {
      const int colg = bn * 64 + wn * 32 + ni * 16 + laneN;
      const float bb = bias[colg];
#pragma unroll
      for (int r = 0; r < 4; ++r) {
        const int rowg = bm * 128 + wm * 64 + mi * 16 + quad * 4 + r;
        Out[(size_t)rowg * 1024 + colg] = acc[mi][ni][r] + bb;
      }
    }
}

// ---------------------------------------------------------------------------
// Flash attention, fp16. R12 = R0's proven structure (512 blocks x 512
// threads, 8 waves x 16 q, 16 waves/CU, double-buffered global_load_lds —
// the only shape that hit 62.8us; R1/R2/R3 restructures all regressed)
// plus ONLY verified micro-opts:
//  - defer-max (THR=8, exp2 domain; P<=2^8 fits fp16) — verified R1/R2
//  - tree max/sum reductions (max3-fusable, shorter dep chains)
//  - rotated stride-64 P strip (conflicts 3.1M->2.1M measured R1)
//  - ALL addresses hoisted: running stage pointers (2 v_adds/kt), frag/P
//    offsets precomputed; kt-loop unrolled x2 via macro so double-buffer
//    LDS bases are compile-time constants (R2 counter read: 265 VALU
//    inst/kt/wave >> ~90 softmax ops — address math dominated VALU).
// LDS 48KB. NO structural change vs R0.
// ---------------------------------------------------------------------------
__global__ __launch_bounds__(512, 4)
void attn(const short* __restrict__ Qf, const short* __restrict__ Kf,
          const short* __restrict__ Vt_, short* __restrict__ Ow) {
  __shared__ short Ks[2 * 4096];     // 2 x 64k x 64d
  __shared__ short Vts[2 * 4096];    // 2 x 64d x 64k
  __shared__ short Ps[8][16 * 64];   // per-wave P strip [q][k], stride 64

  // XCD-locality: 512 blocks, 8 groups x 4 (h,b) pairs x 16 q-tiles
  const int blk = blockIdx.x;
  const int xcd = blk & 7, local = blk >> 3;
  const int pair = xcd * 4 + (local >> 4);
  const int h = pair & 15, b = pair >> 4, qt = local & 15;
  const size_t head = ((size_t)b * H_ + h) * (size_t)S_ * HD_;

  const int t = threadIdx.x;
  const int wave = t >> 6, lane = t & 63;
  const int laneN = lane & 15, quad = lane >> 4;

  // Q frags (B-operand); wave owns 16 q rows
  frag8 qf[2];
  {
    const size_t row = (size_t)qt * 128 + wave * 16 + laneN;
#pragma unroll
    for (int half = 0; half < 2; ++half)
      qf[half] = ld_frag(Qf + head + row * HD_ + half * 32 + quad * 8);
  }

  f32x4 o[4];          // O^T: row d = dt*16+quad*4+r, col q = laneN
  float m_r = -1e30f, l_r = 0.f;
#pragma unroll
  for (int i = 0; i < 4; ++i)
#pragma unroll
    for (int j = 0; j < 4; ++j) o[i][j] = 0.f;

  // ---- hoisted staging addresses: 1 K-chunk + 1 V-chunk per thread ----
  const int srow = t >> 3, sg = (t & 7) ^ (srow & 7);
  const short* kp = Kf + head + (size_t)srow * HD_ + sg * 8;  // += 4096/kt
  const short* vp = Vt_ + head + (size_t)srow * S_ + sg * 8;  // += 64/kt
  const int d = t * 8;                                        // LDS dest

  // ---- hoisted frag read offsets (serve K and V reads; rows nt*16+laneN)
  int off[4][2];
#pragma unroll
  for (int nt = 0; nt < 4; ++nt) {
    const int row = nt * 16 + laneN;
    off[nt][0] = row * 64 + ((quad ^ (row & 7)) * 8);
    off[nt][1] = row * 64 + (((quad + 4) ^ (row & 7)) * 8);
  }

  // ---- hoisted P-strip addresses (rotated slot = (g + q) & 7) ----
  short* const pwr = &Ps[wave][0] + laneN * 64;
  short* pw[4];
#pragma unroll
  for (int nt = 0; nt < 4; ++nt) {
    const int g = nt * 2 + (quad >> 1);
    pw[nt] = pwr + ((g + laneN) & 7) * 8 + (quad & 1) * 4;
  }
  const short* prd0 = pwr + ((quad + laneN) & 7) * 8;        // k 0..31
  const short* prd1 = pwr + (((quad + 4) + laneN) & 7) * 8;  // k 32..63

  // prologue: stage tile 0 into buf0
  async_copy16(kp, Ks + d);
  async_copy16(vp, Vts + d);
  kp += 4096; vp += 64;

// One kt step. RBUF = compile-time read-buffer (0/1); stage targets RBUF^1.
#define ATTN_TILE(RBUF, DO_STAGE)                                            \
  {                                                                          \
    if (DO_STAGE) {                                                          \
      async_copy16(kp, (RBUF ? Ks : Ks + 4096) + d);                         \
      async_copy16(vp, (RBUF ? Vts : Vts + 4096) + d);                       \
      kp += 4096; vp += 64;                                                  \
      WAITCNT_VM(2);                                                         \
    } else {                                                                 \
      WAITCNT_VM(0);                                                         \
    }                                                                        \
    RAW_BARRIER();                                                           \
    const short* KbS = Ks + (RBUF ? 4096 : 0);                               \
    const short* VbS = Vts + (RBUF ? 4096 : 0);                              \
    /* V frags (A-operand of PV): rows d = dt*16+laneN */                    \
    frag8 vf[4][2];                                                          \
    _Pragma("unroll")                                                        \
    for (int dt = 0; dt < 4; ++dt) {                                         \
      vf[dt][0] = ld_frag(VbS + off[dt][0]);                                 \
      vf[dt][1] = ld_frag(VbS + off[dt][1]);                                 \
    }                                                                        \
    /* S^T = K.Q^T: per lane 16 logits for q=laneN, k=nt*16+quad*4+r */      \
    f32x4 s[4];                                                              \
    _Pragma("unroll")                                                        \
    for (int nt = 0; nt < 4; ++nt) {                                         \
      frag8 k0 = ld_frag(KbS + off[nt][0]);                                  \
      frag8 k1 = ld_frag(KbS + off[nt][1]);                                  \
      f32x4 acc = {0.f, 0.f, 0.f, 0.f};                                      \
      acc = mfma_f16(k0, qf[0], acc);                                        \
      acc = mfma_f16(k1, qf[1], acc);                                        \
      s[nt] = acc;                                                           \
    }                                                                        \
    /* online softmax (exp2 domain): tree reduce + defer-max (THR=8) */      \
    {                                                                        \
      float mt[4];                                                           \
      _Pragma("unroll")                                                      \
      for (int nt = 0; nt < 4; ++nt)                                         \
        mt[nt] = fmaxf(fmaxf(s[nt][0], s[nt][1]),                            \
                       fmaxf(s[nt][2], s[nt][3]));                           \
      float mx = fmaxf(fmaxf(mt[0], mt[1]), fmaxf(mt[2], mt[3]));            \
      mx = fmaxf(mx, __shfl_xor(mx, 16));                                    \
      mx = fmaxf(mx, __shfl_xor(mx, 32));                                    \
      if (__any(mx > m_r + 8.f)) {   /* wave-uniform: rescale rarely */      \
        const float mn = fmaxf(m_r, mx);                                     \
        const float al = fast_exp2(m_r - mn);                                \
        m_r = mn;                                                            \
        l_r *= al;                                                           \
        _Pragma("unroll")                                                    \
        for (int dt = 0; dt < 4; ++dt)                                       \
          _Pragma("unroll")                                                  \
          for (int r = 0; r < 4; ++r) o[dt][r] *= al;                        \
      }                                                                      \
      float rt[4];                                                           \
      _Pragma("unroll")                                                      \
      for (int nt = 0; nt < 4; ++nt) {                                       \
        const float p0 = fast_exp2(s[nt][0] - m_r);                          \
        const float p1 = fast_exp2(s[nt][1] - m_r);                          \
        const float p2 = fast_exp2(s[nt][2] - m_r);                          \
        const float p3 = fast_exp2(s[nt][3] - m_r);                          \
        s[nt][0] = p0; s[nt][1] = p1; s[nt][2] = p2; s[nt][3] = p3;          \
        rt[nt] = (p0 + p1) + (p2 + p3);                                      \
      }                                                                      \
      float rs = (rt[0] + rt[1]) + (rt[2] + rt[3]);                          \
      rs += __shfl_xor(rs, 16);                                              \
      rs += __shfl_xor(rs, 32);                                              \
      l_r += rs;                                                             \
    }                                                                        \
    /* P pack: one b64 write per nt at rotated slot (hoisted addr) */        \
    _Pragma("unroll")                                                        \
    for (int nt = 0; nt < 4; ++nt) {                                         \
      i32x2 w;                                                               \
      w[0] = pk2h(s[nt][0], s[nt][1]);                                       \
      w[1] = pk2h(s[nt][2], s[nt][3]);                                       \
      *(i32x2*)pw[nt] = w;                                                   \
    }                                                                        \
    /* B-operand P frags (per-wave strip; in-order DS within a wave) */      \
    const frag8 p0 = ld_frag(prd0);                                          \
    const frag8 p1 = ld_frag(prd1);                                          \
    _Pragma("unroll")                                                        \
    for (int dt = 0; dt < 4; ++dt) {                                         \
      o[dt] = mfma_f16(vf[dt][0], p0, o[dt]);                                \
      o[dt] = mfma_f16(vf[dt][1], p1, o[dt]);                                \
    }                                                                        \
    RAW_BARRIER();                                                           \
  }

  for (int it = 0; it < 15; ++it) {   // tiles 0..29
    ATTN_TILE(0, 1)
    ATTN_TILE(1, 1)
  }
  ATTN_TILE(0, 1)   // tile 30 (stages tile 31)
  ATTN_TILE(1, 0)   // tile 31 (no stage)
#undef ATTN_TILE

  // epilogue: O^T -> Ow[B,S,D] fp16; lane owns q, 4 consecutive d per dt
  {
    const float inv = 1.0f / l_r;
    const int sgq = qt * 128 + wave * 16 + laneN;
    short* dst = Ow + ((size_t)b * S_ + sgq) * D_ + h * HD_;
#pragma unroll
    for (int dt = 0; dt < 4; ++dt) {
      short pk[4] = { f2h(o[dt][0] * inv), f2h(o[dt][1] * inv),
                      f2h(o[dt][2] * inv), f2h(o[dt][3] * inv) };
      i32x2 w; __builtin_memcpy(&w, pk, 8);
      *(i32x2*)(dst + dt * 16 + quad * 4) = w;
    }
  }
}

// ---------------------------------------------------------------------------
extern "C" void kernel_launch(void* const* d_in, const int* in_sizes, int n_in,
                              void* d_out, int out_size, void* d_ws, size_t ws_size,
                              hipStream_t stream) {
  const float* q  = (const float*)d_in[0];
  const float* k  = (const float*)d_in[1];
  const float* v  = (const float*)d_in[2];
  const float* Wq = (const float*)d_in[3];
  const float* bq = (const float*)d_in[4];
  const float* Wk = (const float*)d_in[5];
  const float* bk = (const float*)d_in[6];
  const float* Wv = (const float*)d_in[7];
  const float* bv = (const float*)d_in[8];
  const float* Wo = (const float*)d_in[9];
  const float* bo = (const float*)d_in[10];

  const size_t NTOK = (size_t)B_ * S_ * D_;   // 4,194,304
  const size_t NW   = (size_t)D_ * D_;        // 1,048,576
  short* p = (short*)d_ws;
  short* qh = p; p += NTOK;  short* kh = p; p += NTOK;  short* vh = p; p += NTOK;
  short* wq = p; p += NW;    short* wk = p; p += NW;
  short* wv = p; p += NW;    short* wo = p; p += NW;
  short* Qf = p; p += NTOK;  short* Kf = p; p += NTOK;
  short* Vt = p; p += NTOK;  short* Ow = p; p += NTOK;

  dim3 blk(256);

  conv_all<<<8192, blk, 0, stream>>>(q, k, v, Wq, Wk, Wv, Wo,
                                     qh, kh, vh, wq, wk, wv, wo);

  const float QS = 11.541560327111707f;  // 8 * log2(e): exp2-domain softmax
  gemm_qkv<<<768, blk, 0, stream>>>(qh, kh, vh, wq, wk, wv, bq, bk, bv,
                                    Qf, Kf, Vt, QS);

  attn<<<512, dim3(512), 0, stream>>>(Qf, Kf, Vt, Ow);

  gemm_out<<<512, blk, 0, stream>>>(Ow, wo, bo, (float*)d_out);
}

// Round 5
// 224.237 us; speedup vs baseline: 1.7721x; 1.0051x over previous
//
#include <hip/hip_runtime.h>
#include <type_traits>
#include <utility>

#define B_ 2
#define S_ 2048
#define D_ 1024
#define H_ 16
#define HD_ 64
#define KDIM 1024

typedef __attribute__((ext_vector_type(8))) short    s16x8;
typedef __attribute__((ext_vector_type(8))) _Float16 h16x8;
typedef __attribute__((ext_vector_type(4))) float    f32x4;
typedef __attribute__((ext_vector_type(4))) int      i32x4;
typedef __attribute__((ext_vector_type(2))) int      i32x2;

// --- MFMA operand-type hedge (fp16) ---
template <typename T, typename = void> struct mfma_takes : std::false_type {};
template <typename T>
struct mfma_takes<T, std::void_t<decltype(__builtin_amdgcn_mfma_f32_16x16x32_f16(
    std::declval<T>(), std::declval<T>(), std::declval<f32x4>(), 0, 0, 0))>>
    : std::true_type {};
using frag8 = std::conditional_t<mfma_takes<h16x8>::value, h16x8, s16x8>;

__device__ __forceinline__ f32x4 mfma_f16(frag8 a, frag8 b, f32x4 c) {
  return __builtin_amdgcn_mfma_f32_16x16x32_f16(a, b, c, 0, 0, 0);
}

__device__ __forceinline__ short f2h(float f) {  // RTNE f32 -> fp16 bits
  _Float16 h = (_Float16)f;
  short s; __builtin_memcpy(&s, &h, 2);
  return s;
}
__device__ __forceinline__ int pk2h(float a, float b) {  // v_cvt_pkrtz 2xfp16
  auto p = __builtin_amdgcn_cvt_pkrtz(a, b);   // __fp16 ext_vector(2)
  int r; __builtin_memcpy(&r, &p, 4); return r;
}
__device__ __forceinline__ frag8 ld_frag(const short* p) {
  return __builtin_bit_cast(frag8, *(const i32x4*)p);
}
__device__ __forceinline__ float fast_exp2(float x) {
  return __builtin_amdgcn_exp2f(x);
}

typedef __attribute__((address_space(1))) const void gvoid;
typedef __attribute__((address_space(3))) void lvoid;
__device__ __forceinline__ void async_copy16(const void* g, void* l) {
  __builtin_amdgcn_global_load_lds((gvoid*)g, (lvoid*)l, 16, 0, 0);
}

#define RAW_BARRIER() asm volatile("s_barrier" ::: "memory")
#define WAITCNT_VM(n) asm volatile("s_waitcnt vmcnt(" #n ")" ::: "memory")

// ---------------------------------------------------------------------------
// Fused fp32 -> fp16 converts: q,k,v (2048 blocks each) + 4 weights (512 each)
// ---------------------------------------------------------------------------
__global__ __launch_bounds__(256)
void conv_all(const float* __restrict__ q, const float* __restrict__ k,
              const float* __restrict__ v, const float* __restrict__ Wq,
              const float* __restrict__ Wk, const float* __restrict__ Wv,
              const float* __restrict__ Wo,
              short* __restrict__ qh, short* __restrict__ kh,
              short* __restrict__ vh, short* __restrict__ wq,
              short* __restrict__ wk, short* __restrict__ wv,
              short* __restrict__ wo) {
  const int blk = blockIdx.x;
  const float* src; short* dst; int base;
  if (blk < 2048)      { src = q;  dst = qh; base = blk; }
  else if (blk < 4096) { src = k;  dst = kh; base = blk - 2048; }
  else if (blk < 6144) { src = v;  dst = vh; base = blk - 4096; }
  else if (blk < 6656) { src = Wq; dst = wq; base = blk - 6144; }
  else if (blk < 7168) { src = Wk; dst = wk; base = blk - 6656; }
  else if (blk < 7680) { src = Wv; dst = wv; base = blk - 7168; }
  else                 { src = Wo; dst = wo; base = blk - 7680; }
  const int i = base * 2048 + threadIdx.x * 8;
  float4 a0 = *(const float4*)(src + i);
  float4 a1 = *(const float4*)(src + i + 4);
  short h[8] = { f2h(a0.x), f2h(a0.y), f2h(a0.z), f2h(a0.w),
                 f2h(a1.x), f2h(a1.y), f2h(a1.z), f2h(a1.w) };
  i32x4 ph; __builtin_memcpy(&ph, h, 16);
  *(i32x4*)(dst + i) = ph;
}

// ---------------------------------------------------------------------------
// QKV projection GEMM, fp16 A & W, tile 128x128, BK=32, triple-buffered
// global_load_lds (prefetch distance 2). A-GROUPED XCD DECODE (see R8 note).
// R5: epilogue restaged through per-wave LDS strip -> full-128B-line b128
// stores (was 64x2B scalar stores/thread for Qf/Kf = 12.6M store insts).
// ---------------------------------------------------------------------------
__global__ __launch_bounds__(256, 3)
void gemm_qkv(const short* __restrict__ qh, const short* __restrict__ kh,
              const short* __restrict__ vh, const short* __restrict__ wq,
              const short* __restrict__ wk, const short* __restrict__ wv,
              const float* __restrict__ bq, const float* __restrict__ bk,
              const float* __restrict__ bv, short* __restrict__ Qf,
              short* __restrict__ Kf, short* __restrict__ Vt, float QS) {
  __shared__ short As[3 * 4096];
  __shared__ short Bs[3 * 4096];

  const int blk = blockIdx.x;
  const int xcd = blk & 7, i = blk >> 3;      // i in [0,96)
  const int p = (i >> 3) * 8 + xcd;           // A-tile id, p ≡ xcd (mod 8)
  const int bn = i & 7;
  const int z = p >> 5, bm = p & 31;
  const short* Ap = z == 0 ? qh : z == 1 ? kh : vh;
  const short* Wp = z == 0 ? wq : z == 1 ? wk : wv;
  const float* bias = z == 0 ? bq : z == 1 ? bk : bv;
  short* Out = z == 0 ? Qf : z == 1 ? Kf : Vt;
  const float scale = z == 0 ? QS : 1.0f;
  const int omode = z == 2 ? 2 : 1;

  const int t = threadIdx.x, wave = t >> 6, lane = t & 63;
  const int laneN = lane & 15, quad = lane >> 4;
  const int wm = wave & 1, wn = wave >> 1;

  f32x4 acc[4][4];
#pragma unroll
  for (int i2 = 0; i2 < 4; ++i2)
#pragma unroll
    for (int j = 0; j < 4; ++j)
#pragma unroll
      for (int r = 0; r < 4; ++r) acc[i2][j][r] = 0.f;

  auto stage = [&](int buf, int kk) {   // 4 asyncs/thread per call
#pragma unroll
    for (int j = 0; j < 2; ++j) {
      const int chunk = j * 256 + t;
      const int row = chunk >> 2;
      const int gg = (chunk & 3) ^ ((row >> 1) & 3);
      async_copy16(Ap + (size_t)(bm * 128 + row) * KDIM + kk + gg * 8,
                   As + buf * 4096 + chunk * 8);
      async_copy16(Wp + (size_t)(bn * 128 + row) * KDIM + kk + gg * 8,
                   Bs + buf * 4096 + chunk * 8);
    }
  };

  stage(0, 0);
  stage(1, 32);
  int buf = 0;
  for (int kk = 0; kk < KDIM; kk += 32) {
    if (kk + 64 < KDIM) {
      int nb = buf + 2; if (nb >= 3) nb -= 3;
      stage(nb, kk + 64);
      WAITCNT_VM(8);        // drain current tile (oldest 4 of 12)
    } else if (kk + 32 < KDIM) {
      WAITCNT_VM(4);
    } else {
      WAITCNT_VM(0);
    }
    RAW_BARRIER();

    frag8 aF[4], bF[4];
#pragma unroll
    for (int mi = 0; mi < 4; ++mi) {
      const int row = wm * 64 + mi * 16 + laneN;
      aF[mi] = ld_frag(As + buf * 4096 + row * 32 +
                       ((quad ^ ((row >> 1) & 3)) * 8));
    }
#pragma unroll
    for (int ni = 0; ni < 4; ++ni) {
      const int row = wn * 64 + ni * 16 + laneN;
      bF[ni] = ld_frag(Bs + buf * 4096 + row * 32 +
                       ((quad ^ ((row >> 1) & 3)) * 8));
    }
#pragma unroll
    for (int mi = 0; mi < 4; ++mi)
#pragma unroll
      for (int ni = 0; ni < 4; ++ni)
        acc[mi][ni] = mfma_f16(aF[mi], bF[ni], acc[mi][ni]);
    RAW_BARRIER();
    buf = buf + 1 == 3 ? 0 : buf + 1;
  }

  // ---- Epilogue via per-wave LDS restage (As is free past final barrier).
  // C/D frag: col = laneN, row = quad*4 + r. Strip [16][72] (pad: bank
  // rotation + 16B-aligned rows). Intra-wave DS ordering => no barrier.
  short* scr = As + wave * 1152;
  const int h = bn * 2 + wn;
  if (omode == 2) {
    // Vt [B,H,Hd,S]: restage per ni -> [hd 16][s 64], full-line b128 stores
    const int bidx = bm >> 4;
    const int sbase = (bm * 128 + wm * 64) & 2047;
#pragma unroll
    for (int ni = 0; ni < 4; ++ni) {
      const float bb = bias[bn * 128 + wn * 64 + ni * 16 + laneN];
#pragma unroll
      for (int mi = 0; mi < 4; ++mi) {
        short pk[4];
#pragma unroll
        for (int r = 0; r < 4; ++r) pk[r] = f2h(acc[mi][ni][r] + bb);
        i32x2 w; __builtin_memcpy(&w, pk, 8);
        *(i32x2*)(scr + laneN * 72 + mi * 16 + quad * 4) = w;
      }
#pragma unroll
      for (int j = 0; j < 2; ++j) {
        const int ff = lane * 2 + j, hdr = ff >> 3, ch = ff & 7;
        i32x4 v = *(const i32x4*)(scr + hdr * 72 + ch * 8);
        *(i32x4*)(Vt + (((size_t)(bidx * H_ + h)) * HD_ + ni * 16 + hdr) * S_ +
                  sbase + ch * 8) = v;
      }
    }
  } else {
    // Qf/Kf [B,H,S,Hd]: restage per mi -> [s 16][hd 64], full-line stores
#pragma unroll
    for (int mi = 0; mi < 4; ++mi) {
#pragma unroll
      for (int ni = 0; ni < 4; ++ni) {
        const float bb = bias[bn * 128 + wn * 64 + ni * 16 + laneN];
#pragma unroll
        for (int r = 0; r < 4; ++r)
          scr[(quad * 4 + r) * 72 + ni * 16 + laneN] =
              f2h((acc[mi][ni][r] + bb) * scale);
      }
#pragma unroll
      for (int j = 0; j < 2; ++j) {
        const int ff = lane * 2 + j, row = ff >> 3, ch = ff & 7;
        const int rowg = bm * 128 + wm * 64 + mi * 16 + row;
        const int bidx = rowg >> 11, s = rowg & 2047;
        i32x4 v = *(const i32x4*)(scr + row * 72 + ch * 8);
        *(i32x4*)(Out + (((size_t)(bidx * H_ + h)) * S_ + s) * HD_ + ch * 8) = v;
      }
    }
  }
}

// ---------------------------------------------------------------------------
// O projection: fp16 A x fp16 Wo -> fp32. Tile 128(M)x64(N), triple-buffered
// prefetch distance 2. A-GROUPED XCD DECODE. R5: epilogue restaged through
// per-wave LDS -> full-128B-line f32x4 stores (was 32x4B scalar/thread).
// ---------------------------------------------------------------------------
__global__ __launch_bounds__(256, 3)
void gemm_out(const short* __restrict__ Ap, const short* __restrict__ Wp,
              const float* __restrict__ bias, float* __restrict__ Out) {
  __shared__ short As[3 * 4096];   // 128x32
  __shared__ short Bs[3 * 2048];   // 64x32
  const int blk = blockIdx.x;
  const int xcd = blk & 7, i = blk >> 3;      // i in [0,64)
  const int bm = (i >> 4) * 8 + xcd;          // bm ≡ xcd (mod 8)
  const int bn = i & 15;

  const int t = threadIdx.x, wave = t >> 6, lane = t & 63;
  const int laneN = lane & 15, quad = lane >> 4;
  const int wm = wave & 1, wn = wave >> 1;

  f32x4 acc[4][2];
#pragma unroll
  for (int i2 = 0; i2 < 4; ++i2)
#pragma unroll
    for (int j = 0; j < 2; ++j)
#pragma unroll
      for (int r = 0; r < 4; ++r) acc[i2][j][r] = 0.f;

  auto stage = [&](int buf, int kk) {   // 3 asyncs/thread per call
#pragma unroll
    for (int j = 0; j < 2; ++j) {
      const int chunk = j * 256 + t;
      const int row = chunk >> 2;
      const int gg = (chunk & 3) ^ ((row >> 1) & 3);
      async_copy16(Ap + (size_t)(bm * 128 + row) * KDIM + kk + gg * 8,
                   As + buf * 4096 + chunk * 8);
    }
    {
      const int chunk = t;
      const int row = chunk >> 2;
      const int gg = (chunk & 3) ^ ((row >> 1) & 3);
      async_copy16(Wp + (size_t)(bn * 64 + row) * KDIM + kk + gg * 8,
                   Bs + buf * 2048 + chunk * 8);
    }
  };

  stage(0, 0);
  stage(1, 32);
  int buf = 0;
  for (int kk = 0; kk < KDIM; kk += 32) {
    if (kk + 64 < KDIM) {
      int nb = buf + 2; if (nb >= 3) nb -= 3;
      stage(nb, kk + 64);
      WAITCNT_VM(6);
    } else if (kk + 32 < KDIM) {
      WAITCNT_VM(3);
    } else {
      WAITCNT_VM(0);
    }
    RAW_BARRIER();

    frag8 aF[4], bF[2];
#pragma unroll
    for (int mi = 0; mi < 4; ++mi) {
      const int row = wm * 64 + mi * 16 + laneN;
      aF[mi] = ld_frag(As + buf * 4096 + row * 32 +
                       ((quad ^ ((row >> 1) & 3)) * 8));
    }
#pragma unroll
    for (int ni = 0; ni < 2; ++ni) {
      const int row = wn * 32 + ni * 16 + laneN;
      bF[ni] = ld_frag(Bs + buf * 2048 + row * 32 +
                       ((quad ^ ((row >> 1) & 3)) * 8));
    }
#pragma unroll
    for (int mi = 0; mi < 4; ++mi)
#pragma unroll
      for (int ni = 0; ni < 2; ++ni)
        acc[mi][ni] = mfma_f16(aF[mi], bF[ni], acc[mi][ni]);
    RAW_BARRIER();
    buf = buf + 1 == 3 ? 0 : buf + 1;
  }

  // ---- Epilogue via per-wave LDS restage: [16 rows][36 f32] strip.
  float* scr = (float*)As + wave * 576;
#pragma unroll
  for (int mi = 0; mi < 4; ++mi) {
#pragma unroll
    for (int ni = 0; ni < 2; ++ni) {
      const float bb = bias[bn * 64 + wn * 32 + ni * 16 + laneN];
#pragma unroll
      for (int r = 0; r < 4; ++r)
        scr[(quad * 4 + r) * 36 + ni * 16 + laneN] = acc[mi][ni][r] + bb;
    }
#pragma unroll
    for (int j = 0; j < 2; ++j) {
      const int ff = lane * 2 + j, row = ff >> 3, ch = ff & 7;
      const int rowg = bm * 128 + wm * 64 + mi * 16 + row;
      f32x4 v = *(const f32x4*)(scr + row * 36 + ch * 4);
      *(f32x4*)(Out + (size_t)rowg * 1024 + bn * 64 + wn * 32 + ch * 4) = v;
    }
  }
}

// ---------------------------------------------------------------------------
// Flash attention, fp16. R5: R0's proven shape (512 blocks x 512 threads,
// 8 waves x 16 q, 16 waves/CU) with the barrier count HALVED: 4-deep LDS
// ring (K,V x 4 bufs) + prefetch distance 2 + counted vmcnt(4) -> ONE
// s_barrier per kt (was 2 + full drains; R4 showed address opts neutral =>
// lockstep is the cost). Buffer safety: barrier drift <=1 iter; stage
// target (kt+2)&3 never collides with any wave reading kt or kt-1 (mod-4
// distinct). T5 s_setprio(1) around both MFMA clusters (m191: +4-7% attn).
// Compute bit-identical to R4. LDS 80KB -> still 2 blocks/CU.
// ---------------------------------------------------------------------------
__global__ __launch_bounds__(512, 4)
void attn(const short* __restrict__ Qf, const short* __restrict__ Kf,
          const short* __restrict__ Vt_, short* __restrict__ Ow) {
  __shared__ short Ks[4 * 4096];     // 4 x 64k x 64d
  __shared__ short Vts[4 * 4096];    // 4 x 64d x 64k
  __shared__ short Ps[8][16 * 64];   // per-wave P strip [q][k], stride 64

  // XCD-locality: 512 blocks, 8 groups x 4 (h,b) pairs x 16 q-tiles
  const int blk = blockIdx.x;
  const int xcd = blk & 7, local = blk >> 3;
  const int pair = xcd * 4 + (local >> 4);
  const int h = pair & 15, b = pair >> 4, qt = local & 15;
  const size_t head = ((size_t)b * H_ + h) * (size_t)S_ * HD_;

  const int t = threadIdx.x;
  const int wave = t >> 6, lane = t & 63;
  const int laneN = lane & 15, quad = lane >> 4;

  // Q frags (B-operand); wave owns 16 q rows
  frag8 qf[2];
  {
    const size_t row = (size_t)qt * 128 + wave * 16 + laneN;
#pragma unroll
    for (int half = 0; half < 2; ++half)
      qf[half] = ld_frag(Qf + head + row * HD_ + half * 32 + quad * 8);
  }

  f32x4 o[4];          // O^T: row d = dt*16+quad*4+r, col q = laneN
  float m_r = -1e30f, l_r = 0.f;
#pragma unroll
  for (int i = 0; i < 4; ++i)
#pragma unroll
    for (int j = 0; j < 4; ++j) o[i][j] = 0.f;

  // ---- hoisted staging addresses: 1 K-chunk + 1 V-chunk per thread ----
  const int srow = t >> 3, sg = (t & 7) ^ (srow & 7);
  const short* kp = Kf + head + (size_t)srow * HD_ + sg * 8;  // += 4096/kt
  const short* vp = Vt_ + head + (size_t)srow * S_ + sg * 8;  // += 64/kt
  const int d = t * 8;                                        // LDS dest

  // ---- hoisted frag read offsets (serve K and V reads; rows nt*16+laneN)
  int off[4][2];
#pragma unroll
  for (int nt = 0; nt < 4; ++nt) {
    const int row = nt * 16 + laneN;
    off[nt][0] = row * 64 + ((quad ^ (row & 7)) * 8);
    off[nt][1] = row * 64 + (((quad + 4) ^ (row & 7)) * 8);
  }

  // ---- hoisted P-strip addresses (rotated slot = (g + q) & 7) ----
  short* const pwr = &Ps[wave][0] + laneN * 64;
  short* pw[4];
#pragma unroll
  for (int nt = 0; nt < 4; ++nt) {
    const int g = nt * 2 + (quad >> 1);
    pw[nt] = pwr + ((g + laneN) & 7) * 8 + (quad & 1) * 4;
  }
  const short* prd0 = pwr + ((quad + laneN) & 7) * 8;        // k 0..31
  const short* prd1 = pwr + (((quad + 4) + laneN) & 7) * 8;  // k 32..63

  // prologue: stage tiles 0,1 into bufs 0,1 (prefetch distance 2)
  async_copy16(kp, Ks + d);  async_copy16(vp, Vts + d);
  kp += 4096; vp += 64;
  async_copy16(kp, Ks + 4096 + d);  async_copy16(vp, Vts + 4096 + d);
  kp += 4096; vp += 64;

// One kt step. B0 = compile-time read-buffer (0..3); stage -> (B0+2)&3.
// STG: 1 = stage + vm(4); 2 = tail vm(2); 0 = tail vm(0).
#define ATTN_TILE(B0, STG)                                                   \
  {                                                                          \
    if (STG == 1) {                                                          \
      async_copy16(kp, Ks + (((B0) + 2) & 3) * 4096 + d);                    \
      async_copy16(vp, Vts + (((B0) + 2) & 3) * 4096 + d);                   \
      kp += 4096; vp += 64;                                                  \
      WAITCNT_VM(4);                                                         \
    } else if (STG == 2) {                                                   \
      WAITCNT_VM(2);                                                         \
    } else {                                                                 \
      WAITCNT_VM(0);                                                         \
    }                                                                        \
    RAW_BARRIER();                                                           \
    const short* KbS = Ks + (B0) * 4096;                                     \
    const short* VbS = Vts + (B0) * 4096;                                    \
    /* V frags (A-operand of PV): rows d = dt*16+laneN */                    \
    frag8 vf[4][2];                                                          \
    _Pragma("unroll")                                                        \
    for (int dt = 0; dt < 4; ++dt) {                                         \
      vf[dt][0] = ld_frag(VbS + off[dt][0]);                                 \
      vf[dt][1] = ld_frag(VbS + off[dt][1]);                                 \
    }                                                                        \
    /* S^T = K.Q^T: per lane 16 logits for q=laneN, k=nt*16+quad*4+r */      \
    f32x4 s[4];                                                              \
    __builtin_amdgcn_s_setprio(1);                                           \
    _Pragma("unroll")                                                        \
    for (int nt = 0; nt < 4; ++nt) {                                         \
      frag8 k0 = ld_frag(KbS + off[nt][0]);                                  \
      frag8 k1 = ld_frag(KbS + off[nt][1]);                                  \
      f32x4 acc = {0.f, 0.f, 0.f, 0.f};                                      \
      acc = mfma_f16(k0, qf[0], acc);                                        \
      acc = mfma_f16(k1, qf[1], acc);                                        \
      s[nt] = acc;                                                           \
    }                                                                        \
    __builtin_amdgcn_s_setprio(0);                                           \
    /* online softmax (exp2 domain): tree reduce + defer-max (THR=8) */      \
    {                                                                        \
      float mt[4];                                                           \
      _Pragma("unroll")                                                      \
      for (int nt = 0; nt < 4; ++nt)                                         \
        mt[nt] = fmaxf(fmaxf(s[nt][0], s[nt][1]),                            \
                       fmaxf(s[nt][2], s[nt][3]));                           \
      float mx = fmaxf(fmaxf(mt[0], mt[1]), fmaxf(mt[2], mt[3]));            \
      mx = fmaxf(mx, __shfl_xor(mx, 16));                                    \
      mx = fmaxf(mx, __shfl_xor(mx, 32));                                    \
      if (__any(mx > m_r + 8.f)) {   /* wave-uniform: rescale rarely */      \
        const float mn = fmaxf(m_r, mx);                                     \
        const float al = fast_exp2(m_r - mn);                                \
        m_r = mn;                                                            \
        l_r *= al;                                                           \
        _Pragma("unroll")                                                    \
        for (int dt = 0; dt < 4; ++dt)                                       \
          _Pragma("unroll")                                                  \
          for (int r = 0; r < 4; ++r) o[dt][r] *= al;                        \
      }                                                                      \
      float rt[4];                                                           \
      _Pragma("unroll")                                                      \
      for (int nt = 0; nt < 4; ++nt) {                                       \
        const float p0 = fast_exp2(s[nt][0] - m_r);                          \
        const float p1 = fast_exp2(s[nt][1] - m_r);                          \
        const float p2 = fast_exp2(s[nt][2] - m_r);                          \
        const float p3 = fast_exp2(s[nt][3] - m_r);                          \
        s[nt][0] = p0; s[nt][1] = p1; s[nt][2] = p2; s[nt][3] = p3;          \
        rt[nt] = (p0 + p1) + (p2 + p3);                                      \
      }                                                                      \
      float rs = (rt[0] + rt[1]) + (rt[2] + rt[3]);                          \
      rs += __shfl_xor(rs, 16);                                              \
      rs += __shfl_xor(rs, 32);                                              \
      l_r += rs;                                                             \
    }                                                                        \
    /* P pack: one b64 write per nt at rotated slot (hoisted addr) */        \
    _Pragma("unroll")                                                        \
    for (int nt = 0; nt < 4; ++nt) {                                         \
      i32x2 w;                                                               \
      w[0] = pk2h(s[nt][0], s[nt][1]);                                       \
      w[1] = pk2h(s[nt][2], s[nt][3]);                                       \
      *(i32x2*)pw[nt] = w;                                                   \
    }                                                                        \
    /* B-operand P frags (per-wave strip; in-order DS within a wave) */      \
    const frag8 p0 = ld_frag(prd0);                                          \
    const frag8 p1 = ld_frag(prd1);                                          \
    __builtin_amdgcn_s_setprio(1);                                           \
    _Pragma("unroll")                                                        \
    for (int dt = 0; dt < 4; ++dt) {                                         \
      o[dt] = mfma_f16(vf[dt][0], p0, o[dt]);                                \
      o[dt] = mfma_f16(vf[dt][1], p1, o[dt]);                                \
    }                                                                        \
    __builtin_amdgcn_s_setprio(0);                                           \
  }

  for (int it = 0; it < 7; ++it) {   // kt 0..27 (stages through tile 29)
    ATTN_TILE(0, 1)
    ATTN_TILE(1, 1)
    ATTN_TILE(2, 1)
    ATTN_TILE(3, 1)
  }
  ATTN_TILE(0, 1)   // kt 28 (stages tile 30)
  ATTN_TILE(1, 1)   // kt 29 (stages tile 31)
  ATTN_TILE(2, 2)   // kt 30 (vm2: only stage 31 outstanding)
  ATTN_TILE(3, 0)   // kt 31 (vm0)
#undef ATTN_TILE

  // epilogue: O^T -> Ow[B,S,D] fp16; lane owns q, 4 consecutive d per dt
  {
    const float inv = 1.0f / l_r;
    const int sgq = qt * 128 + wave * 16 + laneN;
    short* dst = Ow + ((size_t)b * S_ + sgq) * D_ + h * HD_;
#pragma unroll
    for (int dt = 0; dt < 4; ++dt) {
      short pk[4] = { f2h(o[dt][0] * inv), f2h(o[dt][1] * inv),
                      f2h(o[dt][2] * inv), f2h(o[dt][3] * inv) };
      i32x2 w; __builtin_memcpy(&w, pk, 8);
      *(i32x2*)(dst + dt * 16 + quad * 4) = w;
    }
  }
}

// ---------------------------------------------------------------------------
extern "C" void kernel_launch(void* const* d_in, const int* in_sizes, int n_in,
                              void* d_out, int out_size, void* d_ws, size_t ws_size,
                              hipStream_t stream) {
  const float* q  = (const float*)d_in[0];
  const float* k  = (const float*)d_in[1];
  const float* v  = (const float*)d_in[2];
  const float* Wq = (const float*)d_in[3];
  const float* bq = (const float*)d_in[4];
  const float* Wk = (const float*)d_in[5];
  const float* bk = (const float*)d_in[6];
  const float* Wv = (const float*)d_in[7];
  const float* bv = (const float*)d_in[8];
  const float* Wo = (const float*)d_in[9];
  const float* bo = (const float*)d_in[10];

  const size_t NTOK = (size_t)B_ * S_ * D_;   // 4,194,304
  const size_t NW   = (size_t)D_ * D_;        // 1,048,576
  short* p = (short*)d_ws;
  short* qh = p; p += NTOK;  short* kh = p; p += NTOK;  short* vh = p; p += NTOK;
  short* wq = p; p += NW;    short* wk = p; p += NW;
  short* wv = p; p += NW;    short* wo = p; p += NW;
  short* Qf = p; p += NTOK;  short* Kf = p; p += NTOK;
  short* Vt = p; p += NTOK;  short* Ow = p; p += NTOK;

  dim3 blk(256);

  conv_all<<<8192, blk, 0, stream>>>(q, k, v, Wq, Wk, Wv, Wo,
                                     qh, kh, vh, wq, wk, wv, wo);

  const float QS = 11.541560327111707f;  // 8 * log2(e): exp2-domain softmax
  gemm_qkv<<<768, blk, 0, stream>>>(qh, kh, vh, wq, wk, wv, bq, bk, bv,
                                    Qf, Kf, Vt, QS);

  attn<<<512, dim3(512), 0, stream>>>(Qf, Kf, Vt, Ow);

  gemm_out<<<512, blk, 0, stream>>>(Ow, wo, bo, (float*)d_out);
}